// Round 9
// baseline (905.363 us; speedup 1.0000x reference)
//
#include <hip/hip_runtime.h>
#include <hip/hip_bf16.h>

typedef __bf16 bf16x8 __attribute__((ext_vector_type(8)));
typedef float f32x4 __attribute__((ext_vector_type(4)));

#define MFMA16(A, B, C) __builtin_amdgcn_mfma_f32_16x16x32_bf16((A), (B), (C), 0, 0, 0)

// raw barrier: drains only LDS ops (lgkm); global prefetch stays in flight.
#define BARRIER_LDS() do { \
    asm volatile("s_waitcnt lgkmcnt(0)" ::: "memory"); \
    __builtin_amdgcn_s_barrier(); \
  } while (0)

namespace {
constexpr int kT = 256, kIN = 128, kHZ = 24;
}

__device__ __forceinline__ float fsig(float v) {
  float e = __builtin_amdgcn_exp2f(-1.44269504088896340736f * v);
  return __builtin_amdgcn_rcpf(1.0f + e);
}
__device__ __forceinline__ float ftanh(float v) {
  float e = __builtin_amdgcn_exp2f(2.88539008177792681472f * v);
  return 1.0f - 2.0f * __builtin_amdgcn_rcpf(e + 1.0f);
}

// -------------------- main fused GRU kernel (r4 structure, polished) ----------
// 64 blocks x 256 threads (4 waves = 1/SIMD: max issue spread per barrier
// group — 8 waves serialize issue 2/SIMD (r2), 1 wave serializes all
// elementwise (r7)). Per step: GEMM1-h (r-chains first, rh published ASAP,
// z-chains fill pre-barrier window), barrier, GEMM2-h, tanh/blend/h-publish,
// then next-step x-GEMM (24 MFMA) fills pre-barrier window. x dist-2, N
// dist-2 via unroll-2 named double buffers (no register copies, no runtime
// buffer indexing).
template<int XF>
__global__ __launch_bounds__(256, 1) void gru_main(
    const float* __restrict__ x, const __bf16* __restrict__ xfrag,
    const float* __restrict__ w_i, const float* __restrict__ w_h,
    const float* __restrict__ bias, const __bf16* __restrict__ Nfrag,
    const float* __restrict__ cvec, float* __restrict__ out)
{
  const int tid = threadIdx.x;
  const int w = tid >> 6;
  const int l = tid & 63;
  const int lrow = l & 15;
  const int lg = l >> 4;
  const int b0 = blockIdx.x * 16;

  __shared__ __align__(16) __bf16 h_bf[16 * 128];   // XOR-swizzled
  __shared__ __align__(16) __bf16 rh_bf[16 * 128];  // XOR-swizzled
  __shared__ __align__(16) float red[4][2][64][4];

  for (int i = tid; i < 16 * 128; i += 256) { h_bf[i] = (__bf16)0.0f; rh_bf[i] = (__bf16)0.0f; }

  // ---- persistent weight fragments, combined K = [x(128); h(128)] ----
  // Wzr nt 0,1 -> z cols 32w+16nt ; nt 2,3 -> r cols 128+32w+16(nt-2)
  bf16x8 Wzr[8][4];
  bf16x8 Wa[8][2];
#pragma unroll
  for (int kc = 0; kc < 8; ++kc) {
#pragma unroll
    for (int nt = 0; nt < 4; ++nt) {
      const int col = (nt < 2) ? (w * 32 + nt * 16 + lrow)
                               : (128 + w * 32 + (nt - 2) * 16 + lrow);
      bf16x8 f;
#pragma unroll
      for (int e = 0; e < 8; ++e) {
        const int k = kc * 32 + lg * 8 + e;
        const float v = (k < 128) ? w_i[k * 384 + col] : w_h[(k - 128) * 384 + col];
        f[e] = (__bf16)v;
      }
      Wzr[kc][nt] = f;
    }
  }
#pragma unroll
  for (int kc = 0; kc < 8; ++kc) {
#pragma unroll
    for (int nt = 0; nt < 2; ++nt) {
      const int col = 256 + w * 32 + nt * 16 + lrow;
      bf16x8 f;
#pragma unroll
      for (int e = 0; e < 8; ++e) {
        const int k = kc * 32 + lg * 8 + e;
        const float v = (k < 128) ? w_i[k * 384 + col] : w_h[(k - 128) * 384 + col];
        f[e] = (__bf16)v;
      }
      Wa[kc][nt] = f;
    }
  }

  float bz[2], br[2], ba[2];
#pragma unroll
  for (int nt = 0; nt < 2; ++nt) {
    bz[nt] = bias[w * 32 + nt * 16 + lrow];
    br[nt] = bias[128 + w * 32 + nt * 16 + lrow];
    ba[nt] = bias[256 + w * 32 + nt * 16 + lrow];
  }

  float hreg[2][4] = {{0.f,0.f,0.f,0.f},{0.f,0.f,0.f,0.f}};
  float zreg[2][4];

  const __bf16* nl = Nfrag + (size_t)w * 1024 + (size_t)l * 8;
  const __bf16* xl = xfrag + (size_t)blockIdx.x * kT * 2048 + (size_t)l * 8;
  const float* xbase = x + ((size_t)(b0 + lrow)) * kT * kIN + lg * 8;

  f32x4 oacc[2] = {{0.f,0.f,0.f,0.f},{0.f,0.f,0.f,0.f}};
  f32x4 xacc1[4], xacc2[2];

  auto load_x = [&](bf16x8 (&dst)[4], int t) {
    if (XF) {
      const __bf16* xp = xl + (size_t)t * 2048;
#pragma unroll
      for (int kc = 0; kc < 4; ++kc) dst[kc] = *(const bf16x8*)(xp + kc * 512);
    } else {
#pragma unroll
      for (int kc = 0; kc < 4; ++kc) {
        const float4* p = (const float4*)(xbase + (size_t)t * kIN + kc * 32);
        const float4 a = p[0], b = p[1];
        bf16x8 f;
        f[0]=(__bf16)a.x; f[1]=(__bf16)a.y; f[2]=(__bf16)a.z; f[3]=(__bf16)a.w;
        f[4]=(__bf16)b.x; f[5]=(__bf16)b.y; f[6]=(__bf16)b.z; f[7]=(__bf16)b.w;
        dst[kc] = f;
      }
    }
  };
  auto load_n = [&](bf16x8 (&dst)[2], int t) {
    const __bf16* np = nl + (size_t)t * 4096;
    dst[0] = *(const bf16x8*)(np);
    dst[1] = *(const bf16x8*)(np + 512);
  };
  auto compute_xacc = [&](const bf16x8 (&xv)[4]) {
#pragma unroll
    for (int nt = 0; nt < 2; ++nt) {
      f32x4 a = {bz[nt], bz[nt], bz[nt], bz[nt]}; xacc1[nt] = a;
      f32x4 b = {br[nt], br[nt], br[nt], br[nt]}; xacc1[2 + nt] = b;
      f32x4 c = {ba[nt], ba[nt], ba[nt], ba[nt]}; xacc2[nt] = c;
    }
#pragma unroll
    for (int kc = 0; kc < 4; ++kc) {
#pragma unroll
      for (int nt = 0; nt < 4; ++nt) xacc1[nt] = MFMA16(xv[kc], Wzr[kc][nt], xacc1[nt]);
#pragma unroll
      for (int nt = 0; nt < 2; ++nt) xacc2[nt] = MFMA16(xv[kc], Wa[kc][nt], xacc2[nt]);
    }
  };

  bf16x8 xP[4], xQ[4], nP[2], nQ[2];

  // ---- prologue ----
  {
    bf16x8 xv0[4];
    load_x(xv0, 0);
    compute_xacc(xv0);          // xacc for step 0
  }
  load_x(xP, 1);                // consumed body A s=0 (x(s+1))
  load_x(xQ, 2);                // consumed body B s=1
  load_n(nP, 0);                // dummy N_{-1} for s=0 (h=0, any finite)
  load_n(nQ, 0);                // N_0 for s=1

  __syncthreads();

  // one step; xbuf holds x(s+1), nbuf holds N_{s-1}
  auto step_body = [&](bf16x8 (&xbuf)[4], bf16x8 (&nbuf)[2], int s) {
    // ---- phase 1: h frags ----
    bf16x8 hf[4];
#pragma unroll
    for (int kc = 0; kc < 4; ++kc) {
      const int idx = (lrow * 128 + kc * 32 + lg * 8) ^ ((lrow & 7) << 3);
      hf[kc] = *(const bf16x8*)(h_bf + idx);
    }
    // fused output: oacc += h_{s-1} @ N_{s-1} (independent)
    oacc[0] = MFMA16(hf[w], nbuf[0], oacc[0]);
    oacc[1] = MFMA16(hf[w], nbuf[1], oacc[1]);
    // r-chains FIRST (critical path to rh publish)
    f32x4 accr[2] = {xacc1[2], xacc1[3]};
#pragma unroll
    for (int kc = 0; kc < 4; ++kc) {
#pragma unroll
      for (int nt = 0; nt < 2; ++nt) accr[nt] = MFMA16(hf[kc], Wzr[kc + 4][nt + 2], accr[nt]);
    }
    // r-sig + rh publish ASAP
#pragma unroll
    for (int nt = 0; nt < 2; ++nt) {
#pragma unroll
      for (int j = 0; j < 4; ++j) {
        const float rr = fsig(accr[nt][j]);
        const float rh = rr * hreg[nt][j];
        const int row = lg * 4 + j;
        const int col = w * 32 + nt * 16 + lrow;
        rh_bf[(row * 128 + col) ^ ((row & 7) << 3)] = (__bf16)rh;
      }
    }
    // z-chains + z-sig fill the pre-barrier window (write latency hides)
    f32x4 accz[2] = {xacc1[0], xacc1[1]};
#pragma unroll
    for (int kc = 0; kc < 4; ++kc) {
#pragma unroll
      for (int nt = 0; nt < 2; ++nt) accz[nt] = MFMA16(hf[kc], Wzr[kc + 4][nt], accz[nt]);
    }
#pragma unroll
    for (int nt = 0; nt < 2; ++nt) {
#pragma unroll
      for (int j = 0; j < 4; ++j) zreg[nt][j] = fsig(accz[nt][j]);
    }
    BARRIER_LDS();
    // ---- phase 2: GEMM2 ----
    bf16x8 rf[4];
#pragma unroll
    for (int kc = 0; kc < 4; ++kc) {
      const int idx = (lrow * 128 + kc * 32 + lg * 8) ^ ((lrow & 7) << 3);
      rf[kc] = *(const bf16x8*)(rh_bf + idx);
    }
    f32x4 acc2[2] = {xacc2[0], xacc2[1]};
#pragma unroll
    for (int kc = 0; kc < 4; ++kc) {
#pragma unroll
      for (int nt = 0; nt < 2; ++nt) acc2[nt] = MFMA16(rf[kc], Wa[kc + 4][nt], acc2[nt]);
    }
    // tanh + blend; publish h
#pragma unroll
    for (int nt = 0; nt < 2; ++nt) {
#pragma unroll
      for (int j = 0; j < 4; ++j) {
        const float a = ftanh(acc2[nt][j]);
        const float hn = fmaf(zreg[nt][j], a - hreg[nt][j], hreg[nt][j]);
        hreg[nt][j] = hn;
        const int row = lg * 4 + j;
        const int col = w * 32 + nt * 16 + lrow;
        h_bf[(row * 128 + col) ^ ((row & 7) << 3)] = (__bf16)hn;
      }
    }
    // x-GEMM for step s+1 fills pre-barrier window (h-write latency hides)
    compute_xacc(xbuf);
    // reloads: xbuf <- x(s+3), nbuf <- N_{s+1}; consumed 2 steps later
    {
      const int tx = (s + 3 < kT) ? (s + 3) : (kT - 1);
      load_x(xbuf, tx);
      const int tn = (s + 1 < kT) ? (s + 1) : (kT - 1);
      load_n(nbuf, tn);
    }
    BARRIER_LDS();
  };

#pragma unroll 1
  for (int t = 0; t < kT; t += 2) {
    step_body(xP, nP, t);
    step_body(xQ, nQ, t + 1);
  }

  // ---- epilogue: final term h_255 @ N_255 (N_255 sits in nP) ----
  {
    const int idx = (lrow * 128 + w * 32 + lg * 8) ^ ((lrow & 7) << 3);
    bf16x8 hlast = *(const bf16x8*)(h_bf + idx);
    oacc[0] = MFMA16(hlast, nP[0], oacc[0]);
    oacc[1] = MFMA16(hlast, nP[1], oacc[1]);
  }
  *(f32x4*)(&red[w][0][l][0]) = oacc[0];
  *(f32x4*)(&red[w][1][l][0]) = oacc[1];
  __syncthreads();
  if (w < 2) {
    const int nt = w;
#pragma unroll
    for (int j = 0; j < 4; ++j) {
      const int row = lg * 4 + j;
      const int col = nt * 16 + lrow;
      if (col < kHZ) {
        const float v = red[0][nt][l][j] + red[1][nt][l][j] +
                        red[2][nt][l][j] + red[3][nt][l][j] + cvec[col];
        out[(size_t)(b0 + row) * kHZ + col] = v;
      }
    }
  }
}

// -------------------- x -> bf16 A-fragment layout --------------------
__global__ __launch_bounds__(256) void xprep(
    const float* __restrict__ x, __bf16* __restrict__ xfrag)
{
  const int bg = blockIdx.x, t = blockIdx.y;
  const int tid = threadIdx.x;
  const int kc = tid >> 6, l = tid & 63;
  const int row = l & 15, lgx = l >> 4;
  const float* src = x + (((size_t)(bg * 16 + row)) * kT + t) * kIN + kc * 32 + lgx * 8;
  const float4 a = ((const float4*)src)[0];
  const float4 b = ((const float4*)src)[1];
  bf16x8 f;
  f[0]=(__bf16)a.x; f[1]=(__bf16)a.y; f[2]=(__bf16)a.z; f[3]=(__bf16)a.w;
  f[4]=(__bf16)b.x; f[5]=(__bf16)b.y; f[6]=(__bf16)b.z; f[7]=(__bf16)b.w;
  *(bf16x8*)(xfrag + ((size_t)bg * kT + t) * 2048 + (size_t)tid * 8) = f;
}

// -------------------- N_t = mlp_w @ (fc_w_t @ out_w), bf16 B-frags --------------------
__global__ __launch_bounds__(256) void nprep(
    const float* __restrict__ mlp_w, const float* __restrict__ fc_w,
    const float* __restrict__ out_w, __bf16* __restrict__ Nfrag)
{
  const int t = blockIdx.x;
  const int tid = threadIdx.x;
  __shared__ __align__(16) float Q[512 * 24];
  __shared__ __align__(16) float obuf[4096];

  float* ow = obuf;
  for (int i = tid; i < 128 * 24; i += 256) ow[i] = out_w[i];
  __syncthreads();

  for (int i = tid; i < 512; i += 256) {
    const float* rowp = fc_w + ((size_t)t * 512 + i) * 128;
    float q[24];
#pragma unroll
    for (int j = 0; j < 24; ++j) q[j] = 0.0f;
    auto acc_m = [&](float rv, int m) {
      const float4* owp = (const float4*)(ow + m * 24);
      const float4 o0 = owp[0], o1 = owp[1], o2 = owp[2];
      const float4 o3 = owp[3], o4 = owp[4], o5 = owp[5];
      q[0]  = fmaf(rv, o0.x, q[0]);  q[1]  = fmaf(rv, o0.y, q[1]);
      q[2]  = fmaf(rv, o0.z, q[2]);  q[3]  = fmaf(rv, o0.w, q[3]);
      q[4]  = fmaf(rv, o1.x, q[4]);  q[5]  = fmaf(rv, o1.y, q[5]);
      q[6]  = fmaf(rv, o1.z, q[6]);  q[7]  = fmaf(rv, o1.w, q[7]);
      q[8]  = fmaf(rv, o2.x, q[8]);  q[9]  = fmaf(rv, o2.y, q[9]);
      q[10] = fmaf(rv, o2.z, q[10]); q[11] = fmaf(rv, o2.w, q[11]);
      q[12] = fmaf(rv, o3.x, q[12]); q[13] = fmaf(rv, o3.y, q[13]);
      q[14] = fmaf(rv, o3.z, q[14]); q[15] = fmaf(rv, o3.w, q[15]);
      q[16] = fmaf(rv, o4.x, q[16]); q[17] = fmaf(rv, o4.y, q[17]);
      q[18] = fmaf(rv, o4.z, q[18]); q[19] = fmaf(rv, o4.w, q[19]);
      q[20] = fmaf(rv, o5.x, q[20]); q[21] = fmaf(rv, o5.y, q[21]);
      q[22] = fmaf(rv, o5.z, q[22]); q[23] = fmaf(rv, o5.w, q[23]);
    };
#pragma unroll 4
    for (int m4 = 0; m4 < 32; ++m4) {
      const float4 rv = *(const float4*)(rowp + m4 * 4);
      acc_m(rv.x, m4 * 4 + 0);
      acc_m(rv.y, m4 * 4 + 1);
      acc_m(rv.z, m4 * 4 + 2);
      acc_m(rv.w, m4 * 4 + 3);
    }
#pragma unroll
    for (int j = 0; j < 24; ++j) Q[i * 24 + j] = q[j];
  }
  __syncthreads();

  {
    const int i = tid & 127;
    const int jh = tid >> 7;
    const float* mrow = mlp_w + (size_t)i * 512;
    float q[12];
#pragma unroll
    for (int j = 0; j < 12; ++j) q[j] = 0.0f;
    auto acc_k = [&](float mv, int k) {
      const float* qrow = Q + (size_t)k * 24 + jh * 12;
      const float4 q0 = *(const float4*)(qrow);
      const float4 q1 = *(const float4*)(qrow + 4);
      const float4 q2 = *(const float4*)(qrow + 8);
      q[0]  = fmaf(mv, q0.x, q[0]);  q[1]  = fmaf(mv, q0.y, q[1]);
      q[2]  = fmaf(mv, q0.z, q[2]);  q[3]  = fmaf(mv, q0.w, q[3]);
      q[4]  = fmaf(mv, q1.x, q[4]);  q[5]  = fmaf(mv, q1.y, q[5]);
      q[6]  = fmaf(mv, q1.z, q[6]);  q[7]  = fmaf(mv, q1.w, q[7]);
      q[8]  = fmaf(mv, q2.x, q[8]);  q[9]  = fmaf(mv, q2.y, q[9]);
      q[10] = fmaf(mv, q2.z, q[10]); q[11] = fmaf(mv, q2.w, q[11]);
    };
#pragma unroll 2
    for (int k4 = 0; k4 < 128; ++k4) {
      const float4 mv = *(const float4*)(mrow + k4 * 4);
      acc_k(mv.x, k4 * 4 + 0);
      acc_k(mv.y, k4 * 4 + 1);
      acc_k(mv.z, k4 * 4 + 2);
      acc_k(mv.w, k4 * 4 + 3);
    }
    float* Nb = obuf;
#pragma unroll
    for (int j = 0; j < 12; ++j) Nb[i * 32 + jh * 12 + j] = q[j];
  }
  for (int idx = tid; idx < 128 * 8; idx += 256) obuf[(idx >> 3) * 32 + 24 + (idx & 7)] = 0.0f;
  __syncthreads();

  {
    const float* Nb = obuf;
#pragma unroll
    for (int u = 0; u < 16; ++u) {
      const int f = tid * 16 + u;
      const int e = f & 7;
      const int lane = (f >> 3) & 63;
      const int nt = (f >> 9) & 1;
      const int kc = f >> 10;
      const int k = kc * 32 + (lane >> 4) * 8 + e;
      const int colj = nt * 16 + (lane & 15);
      Nfrag[(size_t)t * 4096 + f] = (__bf16)Nb[k * 32 + colj];
    }
  }
}

// -------------------- bias constant ----
__global__ __launch_bounds__(256) void bias_partial(
    const float* __restrict__ mlp_b, const float* __restrict__ fc_w,
    float* __restrict__ partial)
{
  const int r0 = blockIdx.x;
  const int tid = threadIdx.x;
  const int m = tid & 127;
  const int g = tid >> 7;
  __shared__ int anynz;
  if (tid == 0) anynz = 0;
  __syncthreads();
  {
    int nz = 0;
    for (int i = tid; i < 512; i += 256) nz |= (mlp_b[i] != 0.0f) ? 1 : 0;
    if (nz) atomicOr(&anynz, 1);
  }
  __syncthreads();
  float acc = 0.0f;
  if (anynz) {
    for (int i = g; i < 512; i += 2)
      acc = fmaf(mlp_b[i], fc_w[((size_t)r0 * 512 + i) * 128 + m], acc);
  }
  __shared__ float sred[2][128];
  sred[g][m] = acc;
  __syncthreads();
  if (g == 0) partial[r0 * 128 + m] = sred[0][m] + sred[1][m];
}

__global__ __launch_bounds__(128) void bias_final(
    const float* __restrict__ fc_b, const float* __restrict__ out_b,
    const float* __restrict__ out_w, const float* __restrict__ partial,
    float* __restrict__ cvec)
{
  const int m = threadIdx.x;
  float s = fc_b[m];
  for (int r0 = 0; r0 < 256; ++r0) s += partial[r0 * 128 + m];
  __shared__ float sm[128];
  sm[m] = s;
  __syncthreads();
  if (m < kHZ) {
    float c = out_b[m];
    for (int k = 0; k < 128; ++k) c = fmaf(sm[k], out_w[k * kHZ + m], c);
    cvec[m] = c;
  }
}

extern "C" void kernel_launch(void* const* d_in, const int* in_sizes, int n_in,
                              void* d_out, int out_size, void* d_ws, size_t ws_size,
                              hipStream_t stream) {
  (void)in_sizes; (void)n_in; (void)out_size;
  const float* x     = (const float*)d_in[0];
  const float* w_i   = (const float*)d_in[1];
  const float* w_h   = (const float*)d_in[2];
  const float* bias  = (const float*)d_in[3];
  const float* mlp_w = (const float*)d_in[4];
  const float* mlp_b = (const float*)d_in[5];
  const float* fc_w  = (const float*)d_in[6];
  const float* fc_b  = (const float*)d_in[7];
  const float* out_w = (const float*)d_in[8];
  const float* out_b = (const float*)d_in[9];
  float* out = (float*)d_out;

  // ws layout: Nfrag (2 MiB) | partial (128 KiB) | cvec (4 KiB) | xfrag (64 MiB)
  const size_t nfrag_b   = (size_t)256 * 4096 * 2;
  const size_t partial_b = (size_t)256 * 128 * 4;
  const size_t cvec_b    = 4096;
  const size_t base_b    = nfrag_b + partial_b + cvec_b;
  const size_t xfrag_b   = (size_t)64 * 256 * 2048 * 2;
  __bf16* Nfrag  = (__bf16*)d_ws;
  float* partial = (float*)((char*)d_ws + nfrag_b);
  float* cvec    = (float*)((char*)d_ws + nfrag_b + partial_b);
  char*  bufp    = (char*)d_ws + base_b;

  nprep<<<256, 256, 0, stream>>>(mlp_w, fc_w, out_w, Nfrag);
  bias_partial<<<256, 256, 0, stream>>>(mlp_b, fc_w, partial);
  bias_final<<<1, 128, 0, stream>>>(fc_b, out_b, out_w, partial, cvec);

  if (ws_size >= base_b + xfrag_b) {
    __bf16* xfrag = (__bf16*)bufp;
    xprep<<<dim3(64, 256), 256, 0, stream>>>(x, xfrag);
    gru_main<1><<<64, 256, 0, stream>>>(x, xfrag, w_i, w_h, bias, Nfrag, cvec, out);
  } else {
    gru_main<0><<<64, 256, 0, stream>>>(x, (const __bf16*)bufp, w_i, w_h, bias, Nfrag, cvec, out);
  }
}

// Round 10
// 648.350 us; speedup vs baseline: 1.3964x; 1.3964x over previous
//
#include <hip/hip_runtime.h>
#include <hip/hip_bf16.h>

typedef __bf16 bf16x8 __attribute__((ext_vector_type(8)));
typedef float f32x4 __attribute__((ext_vector_type(4)));

#define MFMA16(A, B, C) __builtin_amdgcn_mfma_f32_16x16x32_bf16((A), (B), (C), 0, 0, 0)

// raw barrier: drains only LDS ops (lgkm); global prefetch stays in flight.
#define BARRIER_LDS() do { \
    asm volatile("s_waitcnt lgkmcnt(0)" ::: "memory"); \
    __builtin_amdgcn_s_barrier(); \
  } while (0)

namespace {
constexpr int kT = 256, kIN = 128, kHZ = 24;
}

__device__ __forceinline__ float fsig(float v) {
  float e = __builtin_amdgcn_exp2f(-1.44269504088896340736f * v);
  return __builtin_amdgcn_rcpf(1.0f + e);
}
__device__ __forceinline__ float ftanh(float v) {
  float e = __builtin_amdgcn_exp2f(2.88539008177792681472f * v);
  return 1.0f - 2.0f * __builtin_amdgcn_rcpf(e + 1.0f);
}

// -------------------- main fused GRU kernel --------------------
// 64 blocks x 256 threads (4 waves, 1/SIMD). Block owns 16 batch rows, all
// 256 steps. Critical-path engineering:
//  - x-GEMMs (24 MFMA) run one step AHEAD into separate xacc accumulators,
//    overlapping GEMM2/barrier of the current step -> recurrent chain is only
//    4-deep h-MFMAs per GEMM.
//  - x frags prefetched distance-2 (HBM ~900cy), N frags distance-1 (L2).
//  - z,r,a,h for a wave's own 32 columns stay in fp32 registers; LDS carries
//    only bf16 XOR-swizzled h and r*h for cross-wave A-fragments.
// NOTE (r9 lesson): do NOT hand-reorder this body — the compiler's schedule
// of THIS form is the measured optimum (574 us); r9's "polish" cost +25% VALU.
template<int XF>
__global__ __launch_bounds__(256, 1) void gru_main(
    const float* __restrict__ x, const __bf16* __restrict__ xfrag,
    const float* __restrict__ w_i, const float* __restrict__ w_h,
    const float* __restrict__ bias, const __bf16* __restrict__ Nfrag,
    const float* __restrict__ cvec, float* __restrict__ out)
{
  const int tid = threadIdx.x;
  const int w = tid >> 6;      // wave 0..3
  const int l = tid & 63;
  const int lrow = l & 15;     // A-row / C-col lane index
  const int lg = l >> 4;       // k-group
  const int b0 = blockIdx.x * 16;

  __shared__ __align__(16) __bf16 h_bf[16 * 128];   // XOR-swizzled
  __shared__ __align__(16) __bf16 rh_bf[16 * 128];  // XOR-swizzled
  __shared__ __align__(16) float red[4][2][64][4];

  for (int i = tid; i < 16 * 128; i += 256) { h_bf[i] = (__bf16)0.0f; rh_bf[i] = (__bf16)0.0f; }

  // ---- persistent weight fragments. Wzr/Wa kc 0..3 = x half, 4..7 = h half.
  // Wzr tiles: nt 0,1 -> z cols 32w+16nt ; nt 2,3 -> r cols 128+32w+16(nt-2)
  // Wa tiles:  nt 0,1 -> a cols 256+32w+16nt
  bf16x8 Wzr[8][4];
  bf16x8 Wa[8][2];
#pragma unroll
  for (int kc = 0; kc < 8; ++kc) {
#pragma unroll
    for (int nt = 0; nt < 4; ++nt) {
      const int col = (nt < 2) ? (w * 32 + nt * 16 + lrow)
                               : (128 + w * 32 + (nt - 2) * 16 + lrow);
      bf16x8 f;
#pragma unroll
      for (int e = 0; e < 8; ++e) {
        const int k = kc * 32 + lg * 8 + e;
        const float v = (k < 128) ? w_i[k * 384 + col] : w_h[(k - 128) * 384 + col];
        f[e] = (__bf16)v;
      }
      Wzr[kc][nt] = f;
    }
  }
#pragma unroll
  for (int kc = 0; kc < 8; ++kc) {
#pragma unroll
    for (int nt = 0; nt < 2; ++nt) {
      const int col = 256 + w * 32 + nt * 16 + lrow;
      bf16x8 f;
#pragma unroll
      for (int e = 0; e < 8; ++e) {
        const int k = kc * 32 + lg * 8 + e;
        const float v = (k < 128) ? w_i[k * 384 + col] : w_h[(k - 128) * 384 + col];
        f[e] = (__bf16)v;
      }
      Wa[kc][nt] = f;
    }
  }

  float bz[2], br[2], ba[2];
#pragma unroll
  for (int nt = 0; nt < 2; ++nt) {
    bz[nt] = bias[w * 32 + nt * 16 + lrow];
    br[nt] = bias[128 + w * 32 + nt * 16 + lrow];
    ba[nt] = bias[256 + w * 32 + nt * 16 + lrow];
  }

  float hreg[2][4] = {{0.f,0.f,0.f,0.f},{0.f,0.f,0.f,0.f}};
  float zreg[2][4];

  const __bf16* nl = Nfrag + (size_t)w * 1024 + (size_t)l * 8;
  const __bf16* xl = xfrag + (size_t)blockIdx.x * kT * 2048 + (size_t)l * 8;
  const float* xbase = x + ((size_t)(b0 + lrow)) * kT * kIN + lg * 8;

  f32x4 oacc[2] = {{0.f,0.f,0.f,0.f},{0.f,0.f,0.f,0.f}};
  f32x4 xacc1[4], xacc2[2];
  bf16x8 xfA[4], xfB[4], hf[4], rf[4], nCur[2], nB[2];

  // helper: load x fragments for step t into dst
  auto load_x = [&](bf16x8 dst[4], int t) {
    if (XF) {
      const __bf16* xp = xl + (size_t)t * 2048;
#pragma unroll
      for (int kc = 0; kc < 4; ++kc) dst[kc] = *(const bf16x8*)(xp + kc * 512);
    } else {
#pragma unroll
      for (int kc = 0; kc < 4; ++kc) {
        const float4* p = (const float4*)(xbase + (size_t)t * kIN + kc * 32);
        const float4 a = p[0], b = p[1];
        bf16x8 f;
        f[0]=(__bf16)a.x; f[1]=(__bf16)a.y; f[2]=(__bf16)a.z; f[3]=(__bf16)a.w;
        f[4]=(__bf16)b.x; f[5]=(__bf16)b.y; f[6]=(__bf16)b.z; f[7]=(__bf16)b.w;
        dst[kc] = f;
      }
    }
  };
  // helper: xacc(t) = bias + x_t @ W_x  (24 independent MFMAs)
  auto compute_xacc = [&](const bf16x8 xv[4]) {
#pragma unroll
    for (int nt = 0; nt < 2; ++nt) {
      f32x4 a = {bz[nt], bz[nt], bz[nt], bz[nt]}; xacc1[nt] = a;
      f32x4 b = {br[nt], br[nt], br[nt], br[nt]}; xacc1[2 + nt] = b;
      f32x4 c = {ba[nt], ba[nt], ba[nt], ba[nt]}; xacc2[nt] = c;
    }
#pragma unroll
    for (int kc = 0; kc < 4; ++kc) {
#pragma unroll
      for (int nt = 0; nt < 4; ++nt) xacc1[nt] = MFMA16(xv[kc], Wzr[kc][nt], xacc1[nt]);
#pragma unroll
      for (int nt = 0; nt < 2; ++nt) xacc2[nt] = MFMA16(xv[kc], Wa[kc][nt], xacc2[nt]);
    }
  };

  // ---- prologue ----
  {
    bf16x8 xv0[4];
    load_x(xv0, 0);
    compute_xacc(xv0);          // xacc for t=0
  }
  load_x(xfA, 1);               // used by iter 0's x-GEMM (for t=1)
  load_x(xfB, 2);               // used by iter 1
  nCur[0] = *(const bf16x8*)(nl);            // dummy at t=0 (hf=0), finite
  nCur[1] = *(const bf16x8*)(nl + 512);
  nB[0] = nCur[0]; nB[1] = nCur[1];          // N_0, used at iter 1

  __syncthreads();

#pragma unroll 1
  for (int t = 0; t < kT; ++t) {
    // ---- [B] h_{t-1} A-fragments (bf16, swizzled LDS) ----
#pragma unroll
    for (int kc = 0; kc < 4; ++kc) {
      const int idx = (lrow * 128 + kc * 32 + lg * 8) ^ ((lrow & 7) << 3);
      hf[kc] = *(const bf16x8*)(h_bf + idx);
    }
    // ---- [C] GEMM1-h: acc1 = xacc1(t) + h @ W_h_zr  (4-deep chain) ----
    f32x4 acc1[4];
#pragma unroll
    for (int nt = 0; nt < 4; ++nt) acc1[nt] = xacc1[nt];
#pragma unroll
    for (int kc = 0; kc < 4; ++kc) {
#pragma unroll
      for (int nt = 0; nt < 4; ++nt) acc1[nt] = MFMA16(hf[kc], Wzr[kc + 4][nt], acc1[nt]);
    }
    // ---- [D] fused output: oacc += h_{t-1} @ N_{t-1} (independent) ----
    oacc[0] = MFMA16(hf[w], nCur[0], oacc[0]);
    oacc[1] = MFMA16(hf[w], nCur[1], oacc[1]);
    nCur[0] = nB[0]; nCur[1] = nB[1];
    {
      const int tn = (t < kT - 1) ? (t + 1) : (kT - 1);
      const __bf16* np = nl + (size_t)tn * 4096;
      nB[0] = *(const bf16x8*)(np);
      nB[1] = *(const bf16x8*)(np + 512);
    }
    // ---- [E] r-sigmoid + rh write first (critical), z-sigmoid after ----
#pragma unroll
    for (int nt = 0; nt < 2; ++nt) {
#pragma unroll
      for (int j = 0; j < 4; ++j) {
        const float rr = fsig(acc1[2 + nt][j]);
        const float rh = rr * hreg[nt][j];
        const int row = lg * 4 + j;
        const int col = w * 32 + nt * 16 + lrow;
        rh_bf[(row * 128 + col) ^ ((row & 7) << 3)] = (__bf16)rh;
      }
    }
#pragma unroll
    for (int nt = 0; nt < 2; ++nt) {
#pragma unroll
      for (int j = 0; j < 4; ++j) zreg[nt][j] = fsig(acc1[nt][j]);
    }
    BARRIER_LDS();
    // ---- [G] r*h A-fragments ----
#pragma unroll
    for (int kc = 0; kc < 4; ++kc) {
      const int idx = (lrow * 128 + kc * 32 + lg * 8) ^ ((lrow & 7) << 3);
      rf[kc] = *(const bf16x8*)(rh_bf + idx);
    }
    // ---- [H] GEMM2-h: acc2 = xacc2(t) + (r*h) @ W_h_a  (4-deep) ----
    f32x4 acc2[2];
#pragma unroll
    for (int nt = 0; nt < 2; ++nt) acc2[nt] = xacc2[nt];
#pragma unroll
    for (int kc = 0; kc < 4; ++kc) {
#pragma unroll
      for (int nt = 0; nt < 2; ++nt) acc2[nt] = MFMA16(rf[kc], Wa[kc + 4][nt], acc2[nt]);
    }
    // ---- [I] x-GEMMs for t+1 (independent; overlaps [H] chain + barrier) ----
    compute_xacc(xfA);
    // ---- [J] tanh + blend; publish bf16 h ----
#pragma unroll
    for (int nt = 0; nt < 2; ++nt) {
#pragma unroll
      for (int j = 0; j < 4; ++j) {
        const float a = ftanh(acc2[nt][j]);
        const float hn = fmaf(zreg[nt][j], a - hreg[nt][j], hreg[nt][j]);
        hreg[nt][j] = hn;
        const int row = lg * 4 + j;
        const int col = w * 32 + nt * 16 + lrow;
        h_bf[(row * 128 + col) ^ ((row & 7) << 3)] = (__bf16)hn;
      }
    }
    // ---- [K] rotate x buffers, issue distance-2 load ----
#pragma unroll
    for (int kc = 0; kc < 4; ++kc) xfA[kc] = xfB[kc];
    {
      const int tn = (t + 3 < kT) ? (t + 3) : (kT - 1);
      load_x(xfB, tn);
    }
    BARRIER_LDS();
  }

  // ---- epilogue: last term h_{255} @ N_{255}, cross-wave reduce, store ----
  {
    const int idx = (lrow * 128 + w * 32 + lg * 8) ^ ((lrow & 7) << 3);
    bf16x8 hlast = *(const bf16x8*)(h_bf + idx);
    oacc[0] = MFMA16(hlast, nCur[0], oacc[0]);
    oacc[1] = MFMA16(hlast, nCur[1], oacc[1]);
  }
  *(f32x4*)(&red[w][0][l][0]) = oacc[0];
  *(f32x4*)(&red[w][1][l][0]) = oacc[1];
  __syncthreads();
  if (w < 2) {
    const int nt = w;
#pragma unroll
    for (int j = 0; j < 4; ++j) {
      const int row = lg * 4 + j;
      const int col = nt * 16 + lrow;
      if (col < kHZ) {
        const float v = red[0][nt][l][j] + red[1][nt][l][j] +
                        red[2][nt][l][j] + red[3][nt][l][j] + cvec[col];
        out[(size_t)(b0 + row) * kHZ + col] = v;
      }
    }
  }
}

// -------------------- x -> bf16 A-fragment layout --------------------
__global__ __launch_bounds__(256) void xprep(
    const float* __restrict__ x, __bf16* __restrict__ xfrag)
{
  const int bg = blockIdx.x, t = blockIdx.y;
  const int tid = threadIdx.x;
  const int kc = tid >> 6, l = tid & 63;
  const int row = l & 15, lgx = l >> 4;
  const float* src = x + (((size_t)(bg * 16 + row)) * kT + t) * kIN + kc * 32 + lgx * 8;
  const float4 a = ((const float4*)src)[0];
  const float4 b = ((const float4*)src)[1];
  bf16x8 f;
  f[0]=(__bf16)a.x; f[1]=(__bf16)a.y; f[2]=(__bf16)a.z; f[3]=(__bf16)a.w;
  f[4]=(__bf16)b.x; f[5]=(__bf16)b.y; f[6]=(__bf16)b.z; f[7]=(__bf16)b.w;
  *(bf16x8*)(xfrag + ((size_t)bg * kT + t) * 2048 + (size_t)tid * 8) = f;
}

// -------------------- N_t = mlp_w @ (fc_w_t @ out_w), stored as bf16 B-frags --------------------
__global__ __launch_bounds__(256) void nprep(
    const float* __restrict__ mlp_w, const float* __restrict__ fc_w,
    const float* __restrict__ out_w, __bf16* __restrict__ Nfrag)
{
  const int t = blockIdx.x;
  const int tid = threadIdx.x;
  __shared__ __align__(16) float Q[512 * 24];   // 48 KiB
  __shared__ __align__(16) float obuf[4096];    // 16 KiB

  float* ow = obuf;
  for (int i = tid; i < 128 * 24; i += 256) ow[i] = out_w[i];
  __syncthreads();

  for (int i = tid; i < 512; i += 256) {
    const float* rowp = fc_w + ((size_t)t * 512 + i) * 128;
    float q[24];
#pragma unroll
    for (int j = 0; j < 24; ++j) q[j] = 0.0f;
    auto acc_m = [&](float rv, int m) {
      const float4* owp = (const float4*)(ow + m * 24);
      const float4 o0 = owp[0], o1 = owp[1], o2 = owp[2];
      const float4 o3 = owp[3], o4 = owp[4], o5 = owp[5];
      q[0]  = fmaf(rv, o0.x, q[0]);  q[1]  = fmaf(rv, o0.y, q[1]);
      q[2]  = fmaf(rv, o0.z, q[2]);  q[3]  = fmaf(rv, o0.w, q[3]);
      q[4]  = fmaf(rv, o1.x, q[4]);  q[5]  = fmaf(rv, o1.y, q[5]);
      q[6]  = fmaf(rv, o1.z, q[6]);  q[7]  = fmaf(rv, o1.w, q[7]);
      q[8]  = fmaf(rv, o2.x, q[8]);  q[9]  = fmaf(rv, o2.y, q[9]);
      q[10] = fmaf(rv, o2.z, q[10]); q[11] = fmaf(rv, o2.w, q[11]);
      q[12] = fmaf(rv, o3.x, q[12]); q[13] = fmaf(rv, o3.y, q[13]);
      q[14] = fmaf(rv, o3.z, q[14]); q[15] = fmaf(rv, o3.w, q[15]);
      q[16] = fmaf(rv, o4.x, q[16]); q[17] = fmaf(rv, o4.y, q[17]);
      q[18] = fmaf(rv, o4.z, q[18]); q[19] = fmaf(rv, o4.w, q[19]);
      q[20] = fmaf(rv, o5.x, q[20]); q[21] = fmaf(rv, o5.y, q[21]);
      q[22] = fmaf(rv, o5.z, q[22]); q[23] = fmaf(rv, o5.w, q[23]);
    };
#pragma unroll 4
    for (int m4 = 0; m4 < 32; ++m4) {
      const float4 rv = *(const float4*)(rowp + m4 * 4);
      acc_m(rv.x, m4 * 4 + 0);
      acc_m(rv.y, m4 * 4 + 1);
      acc_m(rv.z, m4 * 4 + 2);
      acc_m(rv.w, m4 * 4 + 3);
    }
#pragma unroll
    for (int j = 0; j < 24; ++j) Q[i * 24 + j] = q[j];
  }
  __syncthreads();

  {
    const int i = tid & 127;
    const int jh = tid >> 7;
    const float* mrow = mlp_w + (size_t)i * 512;
    float q[12];
#pragma unroll
    for (int j = 0; j < 12; ++j) q[j] = 0.0f;
    auto acc_k = [&](float mv, int k) {
      const float* qrow = Q + (size_t)k * 24 + jh * 12;
      const float4 q0 = *(const float4*)(qrow);
      const float4 q1 = *(const float4*)(qrow + 4);
      const float4 q2 = *(const float4*)(qrow + 8);
      q[0]  = fmaf(mv, q0.x, q[0]);  q[1]  = fmaf(mv, q0.y, q[1]);
      q[2]  = fmaf(mv, q0.z, q[2]);  q[3]  = fmaf(mv, q0.w, q[3]);
      q[4]  = fmaf(mv, q1.x, q[4]);  q[5]  = fmaf(mv, q1.y, q[5]);
      q[6]  = fmaf(mv, q1.z, q[6]);  q[7]  = fmaf(mv, q1.w, q[7]);
      q[8]  = fmaf(mv, q2.x, q[8]);  q[9]  = fmaf(mv, q2.y, q[9]);
      q[10] = fmaf(mv, q2.z, q[10]); q[11] = fmaf(mv, q2.w, q[11]);
    };
#pragma unroll 2
    for (int k4 = 0; k4 < 128; ++k4) {
      const float4 mv = *(const float4*)(mrow + k4 * 4);
      acc_k(mv.x, k4 * 4 + 0);
      acc_k(mv.y, k4 * 4 + 1);
      acc_k(mv.z, k4 * 4 + 2);
      acc_k(mv.w, k4 * 4 + 3);
    }
    float* Nb = obuf;
#pragma unroll
    for (int j = 0; j < 12; ++j) Nb[i * 32 + jh * 12 + j] = q[j];
  }
  for (int idx = tid; idx < 128 * 8; idx += 256) obuf[(idx >> 3) * 32 + 24 + (idx & 7)] = 0.0f;
  __syncthreads();

  {
    const float* Nb = obuf;
#pragma unroll
    for (int u = 0; u < 16; ++u) {
      const int f = tid * 16 + u;
      const int e = f & 7;
      const int lane = (f >> 3) & 63;
      const int nt = (f >> 9) & 1;
      const int kc = f >> 10;
      const int k = kc * 32 + (lane >> 4) * 8 + e;
      const int colj = nt * 16 + (lane & 15);
      Nfrag[(size_t)t * 4096 + f] = (__bf16)Nb[k * 32 + colj];
    }
  }
}

// -------------------- bias constant ----
__global__ __launch_bounds__(256) void bias_partial(
    const float* __restrict__ mlp_b, const float* __restrict__ fc_w,
    float* __restrict__ partial)
{
  const int r0 = blockIdx.x;
  const int tid = threadIdx.x;
  const int m = tid & 127;
  const int g = tid >> 7;
  __shared__ int anynz;
  if (tid == 0) anynz = 0;
  __syncthreads();
  {
    int nz = 0;
    for (int i = tid; i < 512; i += 256) nz |= (mlp_b[i] != 0.0f) ? 1 : 0;
    if (nz) atomicOr(&anynz, 1);
  }
  __syncthreads();
  float acc = 0.0f;
  if (anynz) {
    for (int i = g; i < 512; i += 2)
      acc = fmaf(mlp_b[i], fc_w[((size_t)r0 * 512 + i) * 128 + m], acc);
  }
  __shared__ float sred[2][128];
  sred[g][m] = acc;
  __syncthreads();
  if (g == 0) partial[r0 * 128 + m] = sred[0][m] + sred[1][m];
}

__global__ __launch_bounds__(128) void bias_final(
    const float* __restrict__ fc_b, const float* __restrict__ out_b,
    const float* __restrict__ out_w, const float* __restrict__ partial,
    float* __restrict__ cvec)
{
  const int m = threadIdx.x;
  float s = fc_b[m];
  for (int r0 = 0; r0 < 256; ++r0) s += partial[r0 * 128 + m];
  __shared__ float sm[128];
  sm[m] = s;
  __syncthreads();
  if (m < kHZ) {
    float c = out_b[m];
    for (int k = 0; k < 128; ++k) c = fmaf(sm[k], out_w[k * kHZ + m], c);
    cvec[m] = c;
  }
}

extern "C" void kernel_launch(void* const* d_in, const int* in_sizes, int n_in,
                              void* d_out, int out_size, void* d_ws, size_t ws_size,
                              hipStream_t stream) {
  (void)in_sizes; (void)n_in; (void)out_size;
  const float* x     = (const float*)d_in[0];
  const float* w_i   = (const float*)d_in[1];
  const float* w_h   = (const float*)d_in[2];
  const float* bias  = (const float*)d_in[3];
  const float* mlp_w = (const float*)d_in[4];
  const float* mlp_b = (const float*)d_in[5];
  const float* fc_w  = (const float*)d_in[6];
  const float* fc_b  = (const float*)d_in[7];
  const float* out_w = (const float*)d_in[8];
  const float* out_b = (const float*)d_in[9];
  float* out = (float*)d_out;

  // workspace: Nfrag (2 MiB) | partial (128 KiB) | cvec (4 KiB) | xfrag (64 MiB)
  const size_t nfrag_b   = (size_t)256 * 4096 * 2;
  const size_t partial_b = (size_t)256 * 128 * 4;
  const size_t cvec_b    = 4096;
  const size_t xfrag_b   = (size_t)64 * 256 * 2048 * 2;
  __bf16* Nfrag  = (__bf16*)d_ws;
  float* partial = (float*)((char*)d_ws + nfrag_b);
  float* cvec    = (float*)((char*)d_ws + nfrag_b + partial_b);
  __bf16* xfrag  = (__bf16*)((char*)d_ws + nfrag_b + partial_b + cvec_b);
  const bool use_xf = ws_size >= nfrag_b + partial_b + cvec_b + xfrag_b;

  nprep<<<256, 256, 0, stream>>>(mlp_w, fc_w, out_w, Nfrag);
  bias_partial<<<256, 256, 0, stream>>>(mlp_b, fc_w, partial);
  bias_final<<<1, 128, 0, stream>>>(fc_b, out_b, out_w, partial, cvec);
  if (use_xf) {
    xprep<<<dim3(64, 256), 256, 0, stream>>>(x, xfrag);
    gru_main<1><<<64, 256, 0, stream>>>(x, xfrag, w_i, w_h, bias, Nfrag, cvec, out);
  } else {
    gru_main<0><<<64, 256, 0, stream>>>(x, xfrag, w_i, w_h, bias, Nfrag, cvec, out);
  }
}